// Round 7
// baseline (1414.466 us; speedup 1.0000x reference)
//
#include <hip/hip_runtime.h>
#include <cmath>

// CfC-NCP RNN, single-kernel-per-chunk pipeline (R6):
//   pack (once): packed-column weight fragments -> h8 in ws; mats pre-scaled
//   (-2*w1, -2*w2, -(ts*wa+wb)) so epilogue is exp-form directly.
//   Launches: pack, then R(c) for c=-1..NCH:
//     WGs 0-15 : r0(c)  = layer0 recurrence + FUSED x1(c) (reuses A-fragments,
//                writes XU1[c&1]); h kept in LDS, NO NH0 round-trip.
//     WGs 16-31: r12(c-1) = layer1 waves 0-6 + layer2 wave 7, reads XU1[(c-1)&1].
//     WGs 32-159: x0(c+1) = parallel GEMM x->XU0[(c+1)&1] on otherwise-idle CUs.
//   XU0/XU1 double-buffered by chunk parity -> same-launch overlap is race-free.
// TC=64, NCH=8 (small pipeline tail). fp16 MFMA inputs, fp32 accum. ws ~50MB.
// R1: raw lgkmcnt-only barrier. R2: packed weights + pipe interleave.
// R3: WG-split pipelining. R4: wa/wb merge + bias folding. R5: depth-2 XU
// prefetch + single-rcp epilogue.

typedef _Float16 f16;
typedef f16 h4 __attribute__((ext_vector_type(4)));
typedef f16 h8 __attribute__((ext_vector_type(8)));
typedef float f4 __attribute__((ext_vector_type(4)));

#define MFMA(a, b, c) __builtin_amdgcn_mfma_f32_16x16x32_f16(a, b, c, 0, 0, 0)
// LDS-only barrier: waves drain their own LDS ops then sync; global loads/stores
// (XU prefetch, XU1/y stores) intentionally left in flight.
#define RAW_BAR() asm volatile("s_waitcnt lgkmcnt(0)\n\ts_barrier" ::: "memory")

constexpr int IN_DIM = 128, Ni = 149, Nc = 99, Nm = 8;
constexpr int CAT0 = 277, CAT1 = 248, CAT2 = 107;
constexpr int Bsz = 256, Tsz = 512;
constexpr int TC = 64, NCH = 8, NBT = 16;
constexpr int NT0P = 28;                 // packed x0 tiles: 3*149=447 cols -> 28
constexpr int NT1P = 19;                 // packed x1 tiles: 3*99=297 cols -> 19
constexpr int S0 = 168, S2 = 136;        // LDS row strides (halves)
constexpr size_t XU0_H = (size_t)TC * NBT * NT0P * 256;  // 7,340,032 halves/buf
constexpr size_t XU1_H = (size_t)TC * NBT * NT1P * 256;  // 4,980,736 halves/buf
constexpr size_t H0S_H = (size_t)NBT * 16 * S0;
constexpr size_t H12S_H = (size_t)NBT * 2 * 16 * S2;
constexpr size_t YOFF = (size_t)Bsz * Tsz * 8;  // h_out offset in d_out
constexpr size_t XUST0 = (size_t)NBT * NT0P * 256;  // per-t stride, halves
constexpr size_t XUST1 = (size_t)NBT * NT1P * 256;

// packed-fragment segment offsets (h8 units)
constexpr int OFF_X0 = 0;          // [ti28][kt4][lane64]
constexpr int OFF_R0 = 7168;       // [g10][mat3][kt5][lane64]
constexpr int OFF_X1 = 16768;      // [ti19][kt5][lane64]
constexpr int OFF_R12A = 22848;    // [w7][mat3][kt4][lane64]
constexpr int OFF_R12B = 28224;    // [mat3][kt4][lane64]
constexpr int NFRAG = 28992;

__device__ inline float rcpf_(float x) { return __builtin_amdgcn_rcpf(x); }
// h = ff1 + (ff2-ff1)*ti with ff=(1-e)/(1+e), ti=1/(1+e2); a0=-2u1, a1=-2u2, a2=-z
__device__ __forceinline__ float cfc_h(float a0, float a1, float a2) {
  float e0 = __expf(a0), e1 = __expf(a1), e2 = __expf(a2);
  float pa = 1.f + e0, ma = 1.f - e0;
  float pb = 1.f + e1, mb = 1.f - e1;
  float pc = 1.f + e2;
  float num = fmaf(ma * pb, e2, mb * pa);
  return num * rcpf_(pa * pb * pc);
}
__device__ __forceinline__ float tanhp_(float x) {
  float e = __expf(-2.f * x);
  return (1.f - e) * rcpf_(1.f + e);
}
// bias for packed output col j (period = in-cols per mat), pre-scaled
__device__ __forceinline__ float xbias(int j, int period, int maxj,
                                       const float* b1, const float* b2,
                                       const float* ba, const float* bb, float ts) {
  if (j >= maxj) return 0.f;
  int mat = j / period, nn = j - mat * period;
  if (mat == 0) return -2.f * b1[nn];
  if (mat == 1) return -2.f * b2[nn];
  return -(ts * ba[nn] + bb[nn]);
}

// ---------------- pack: build all h8 weight fragments once per call ------------------
__global__ __launch_bounds__(256) void pack_kernel(
    const float* __restrict__ w1_0, const float* __restrict__ w2_0,
    const float* __restrict__ wa_0, const float* __restrict__ wb_0,
    const int* __restrict__ m0,
    const float* __restrict__ w1_1, const float* __restrict__ w2_1,
    const float* __restrict__ wa_1, const float* __restrict__ wb_1,
    const int* __restrict__ m1,
    const float* __restrict__ w1_2, const float* __restrict__ w2_2,
    const float* __restrict__ wa_2, const float* __restrict__ wb_2,
    const int* __restrict__ m2, const float* __restrict__ dtp,
    f16* __restrict__ PK) {
  int idx = blockIdx.x * 256 + threadIdx.x;
  if (idx >= NFRAG) return;
  int lane = idx & 63, col = lane & 15, q = lane >> 4;
  float ts = dtp[0];
  const float* W1;  const float* W2;  const float* Wa;  const float* Wb;
  const int* M = nullptr;
  int ld, n = 0, mat = 0, k0 = 0, kmax = 0;
  bool valid = true;
  if (idx < OFF_R0) {  // x0 input-part, packed cols
    int p = idx >> 6;
    int ti = p >> 2, kt = p & 3;
    int j = ti * 16 + col;
    W1 = w1_0; W2 = w2_0; Wa = wa_0; Wb = wb_0;
    ld = CAT0; kmax = IN_DIM; k0 = kt * 32 + q * 8;
    if (j < 447) { mat = j / 149; n = j - mat * 149; if (mat < 2) M = m0; }
    else valid = false;
  } else if (idx < OFF_X1) {  // r0 recurrent-part
    int p = (idx - OFF_R0) >> 6;
    int g = p / 15; mat = (p / 5) % 3; int kt = p % 5;
    W1 = w1_0; W2 = w2_0; Wa = wa_0; Wb = wb_0;
    ld = CAT0; kmax = CAT0; k0 = IN_DIM + kt * 32 + q * 8;
    n = g * 16 + col;
    if (n >= Ni) valid = false;
  } else if (idx < OFF_R12A) {  // x1 input-part, packed cols
    int p = (idx - OFF_X1) >> 6;
    int ti = p / 5, kt = p % 5;
    int j = ti * 16 + col;
    W1 = w1_1; W2 = w2_1; Wa = wa_1; Wb = wb_1;
    ld = CAT1; kmax = Ni; k0 = kt * 32 + q * 8;
    if (j < 297) { mat = j / 99; n = j - mat * 99; if (mat < 2) M = m1; }
    else valid = false;
  } else if (idx < OFF_R12B) {  // r12 layer1 recurrent-part
    int p = (idx - OFF_R12A) >> 6;
    int w = p / 12; mat = (p / 4) % 3; int kt = p & 3;
    W1 = w1_1; W2 = w2_1; Wa = wa_1; Wb = wb_1;
    ld = CAT1; kmax = CAT1; k0 = Ni + kt * 32 + q * 8;
    n = w * 16 + col;
    if (n >= Nc) valid = false;
  } else {  // r12 layer2 (full cat)
    int p = (idx - OFF_R12B) >> 6;
    mat = p / 4; int kt = p & 3;
    W1 = w1_2; W2 = w2_2; Wa = wa_2; Wb = wb_2;
    ld = CAT2; kmax = CAT2; k0 = kt * 32 + q * 8;
    n = col;
    if (n >= Nm) valid = false;
    else if (mat < 2) M = m2;
  }
  h8 r;
#pragma unroll
  for (int j = 0; j < 8; j++) {
    int k = k0 + j;
    float v = 0.f;
    if (valid && k < kmax) {
      if (mat == 0) v = -2.f * W1[(size_t)n * ld + k];
      else if (mat == 1) v = -2.f * W2[(size_t)n * ld + k];
      else v = -(ts * Wa[(size_t)n * ld + k] + Wb[(size_t)n * ld + k]);
      if (M) v *= (float)M[(size_t)n * ld + k];
    }
    r[j] = (f16)v;
  }
  ((h8*)PK)[idx] = r;
}

// ------- r0 one step: recurrence + fused x1 (reuses A-fragments) ---------------------
__device__ __forceinline__ void r0_step(
    const f16* br, f16* bw, const f16* const (&xub)[3], int tload,
    const h8 (&Bf)[3][5], h4 (&xu)[3],
    const h8 (&Bfx)[2][5], const float (&bx)[2], f16* const (&stx)[2],
    int tstore, bool do_x1, bool skip2,
    float* __restrict__ out, int bt, int q, int col, int n, bool last) {
  h8 A[5];
#pragma unroll
  for (int kt = 0; kt < 5; kt++)
    A[kt] = *(const h8*)(br + col * S0 + kt * 32 + q * 8);
  f4 a0 = {(float)xu[0][0], (float)xu[0][1], (float)xu[0][2], (float)xu[0][3]};
  f4 a1 = {(float)xu[1][0], (float)xu[1][1], (float)xu[1][2], (float)xu[1][3]};
  f4 a2 = {(float)xu[2][0], (float)xu[2][1], (float)xu[2][2], (float)xu[2][3]};
#pragma unroll
  for (int mat = 0; mat < 3; mat++)
    xu[mat] = *(const h4*)(xub[mat] + (size_t)tload * XUST0);
#pragma unroll
  for (int kt = 0; kt < 5; kt++) {
    a0 = MFMA(A[kt], Bf[0][kt], a0);
    a1 = MFMA(A[kt], Bf[1][kt], a1);
    a2 = MFMA(A[kt], Bf[2][kt], a2);
  }
  if (do_x1) {  // x1 for time tstore (A = h(tstore)); independent of epilogue
#pragma unroll
    for (int tt = 0; tt < 2; tt++) {
      float b = bx[tt];
      f4 ax = {b, b, b, b};
#pragma unroll
      for (int kt = 0; kt < 5; kt++) ax = MFMA(A[kt], Bfx[tt][kt], ax);
      h4 o;
#pragma unroll
      for (int rr = 0; rr < 4; rr++) o[rr] = (f16)ax[rr];
      if (!(skip2 && tt == 1))
        *(h4*)(stx[tt] + (size_t)tstore * XUST1) = o;
    }
  }
#pragma unroll
  for (int r = 0; r < 4; r++) {
    int m = q * 4 + r;
    float h = cfc_h(a0[r], a1[r], a2[r]);
    f16 h16 = (f16)h;
    bw[m * S0 + n] = h16;
    if (last && n < Ni) out[YOFF + (size_t)(bt * 16 + m) * 256 + n] = h;
  }
}

// ------- r12 layer1 one step ---------------------------------------------------------
__device__ __forceinline__ void r12l1_step(
    const f16* br, f16* bw, const f16* const (&xub)[3], int tload,
    const h8 (&Bf)[3][4], h4 (&xu)[3],
    float* __restrict__ out, int bt, int q, int col, int n, bool last) {
  h8 A[4];
#pragma unroll
  for (int kt = 0; kt < 4; kt++)
    A[kt] = *(const h8*)(br + col * S2 + kt * 32 + q * 8);
  f4 a0 = {(float)xu[0][0], (float)xu[0][1], (float)xu[0][2], (float)xu[0][3]};
  f4 a1 = {(float)xu[1][0], (float)xu[1][1], (float)xu[1][2], (float)xu[1][3]};
  f4 a2 = {(float)xu[2][0], (float)xu[2][1], (float)xu[2][2], (float)xu[2][3]};
#pragma unroll
  for (int mat = 0; mat < 3; mat++)
    xu[mat] = *(const h4*)(xub[mat] + (size_t)tload * XUST1);
#pragma unroll
  for (int kt = 0; kt < 4; kt++) {
    a0 = MFMA(A[kt], Bf[0][kt], a0);
    a1 = MFMA(A[kt], Bf[1][kt], a1);
    a2 = MFMA(A[kt], Bf[2][kt], a2);
  }
#pragma unroll
  for (int r = 0; r < 4; r++) {
    int m = q * 4 + r;
    float h = cfc_h(a0[r], a1[r], a2[r]);
    if (n < Nc) {
      bw[m * S2 + n] = (f16)h;
      if (last) out[YOFF + (size_t)(bt * 16 + m) * 256 + Ni + n] = h;
    }
  }
}

// ------- r12 layer2 one step ---------------------------------------------------------
__device__ __forceinline__ void r12l2_step(
    const f16* rb, f16* wb, float* __restrict__ out, const h8 (&Bf)[3][4],
    float bn0, float bn1, float bn2, int tg, int bt, int col, int q, bool last) {
  h8 A[4];
#pragma unroll
  for (int kt = 0; kt < 4; kt++)
    A[kt] = *(const h8*)(rb + col * S2 + kt * 32 + q * 8);
  f4 a0 = {bn0, bn0, bn0, bn0};
  f4 a1 = {bn1, bn1, bn1, bn1};
  f4 a2 = {bn2, bn2, bn2, bn2};
#pragma unroll
  for (int kt = 0; kt < 4; kt++) {
    a0 = MFMA(A[kt], Bf[0][kt], a0);
    a1 = MFMA(A[kt], Bf[1][kt], a1);
    a2 = MFMA(A[kt], Bf[2][kt], a2);
  }
#pragma unroll
  for (int r = 0; r < 4; r++) {
    int m = q * 4 + r;
    float h = cfc_h(a0[r], a1[r], a2[r]);
    if (col < Nm) {
      out[((size_t)(bt * 16 + m) * Tsz + tg) * 8 + col] = tanhp_(h);
      wb[m * S2 + Nc + col] = (f16)h;
      if (last) out[YOFF + (size_t)(bt * 16 + m) * 256 + Ni + Nc + col] = h;
    }
  }
}

// ---------------- R: [r0(c)+x1 | r12(c-1) | x0(c+1)] ---------------------------------
__global__ __launch_bounds__(640, 3) void R_kernel(
    const h8* __restrict__ pk, const float* __restrict__ x,
    const float* __restrict__ b1_0, const float* __restrict__ b2_0,
    const float* __restrict__ ba_0, const float* __restrict__ bb_0,
    const float* __restrict__ b1_1, const float* __restrict__ b2_1,
    const float* __restrict__ ba_1, const float* __restrict__ bb_1,
    const float* __restrict__ c1, const float* __restrict__ c2,
    const float* __restrict__ ca, const float* __restrict__ cb,
    const float* __restrict__ dtp,
    f16* __restrict__ XU0a, f16* __restrict__ XU0b,
    f16* __restrict__ XU1a, f16* __restrict__ XU1b,
    f16* __restrict__ H0S, f16* __restrict__ H12S,
    float* __restrict__ out, int c) {
  __shared__ __align__(16) char smem[2 * 16 * S0 * 2];
  int tid = threadIdx.x;
  int g = tid >> 6, lane = tid & 63, col = lane & 15, q = lane >> 4;
  int wg = blockIdx.x;
  float ts = dtp[0];

  if (wg < NBT) {  // ================= r0(c) + fused x1(c) =================
    if (c < 0 || c >= NCH) return;
    f16(*buf)[16 * S0] = (f16(*)[16 * S0])smem;
    int bt = wg;
    int n = g * 16 + col;
    const f16* XU0r = (c & 1) ? XU0b : XU0a;
    f16* XU1w = (c & 1) ? XU1b : XU1a;
    h8 Bf[3][5];
#pragma unroll
    for (int mat = 0; mat < 3; mat++)
#pragma unroll
      for (int kt = 0; kt < 5; kt++)
        Bf[mat][kt] = pk[OFF_R0 + ((g * 3 + mat) * 5 + kt) * 64 + lane];
    // fused-x1 tiles: waves 0-8 -> {2g,2g+1}, wave 9 -> {18, dup}
    bool skip2 = (g == 9);
    int ti0 = skip2 ? 18 : 2 * g;
    int ti1 = skip2 ? 18 : 2 * g + 1;
    h8 Bfx[2][5];
    float bx[2];
    f16* stx[2];
    {
      int tis[2] = {ti0, ti1};
#pragma unroll
      for (int tt = 0; tt < 2; tt++) {
#pragma unroll
        for (int kt = 0; kt < 5; kt++)
          Bfx[tt][kt] = pk[OFF_X1 + (tis[tt] * 5 + kt) * 64 + lane];
        bx[tt] = xbias(tis[tt] * 16 + col, 99, 297, b1_1, b2_1, ba_1, bb_1, ts);
        stx[tt] = XU1w + ((size_t)bt * NT1P + tis[tt]) * 256 + lane * 4;
      }
    }
    // xu read bases (packed cols)
    const f16* xub[3];
    {
      int nn = n < 148 ? n : 148;
#pragma unroll
      for (int mat = 0; mat < 3; mat++) {
        int cm = mat * 149 + nn;
        xub[mat] = XU0r + ((size_t)bt * NT0P + (cm >> 4)) * 256 +
                   (q * 16 + (cm & 15)) * 4;
      }
    }
    for (int idx = tid; idx < 16 * S0; idx += 640) {
      buf[0][idx] = (c == 0) ? (f16)0.f : H0S[(size_t)bt * 16 * S0 + idx];
      buf[1][idx] = (f16)0.f;
    }
    __syncthreads();

    h4 xuA[3], xuB[3];
#pragma unroll
    for (int mat = 0; mat < 3; mat++) {
      xuA[mat] = *(const h4*)(xub[mat]);
      xuB[mat] = *(const h4*)(xub[mat] + XUST1 * 0 + XUST0);
    }

    for (int t = 0; t < TC; t += 2) {
      int tlA = (t + 2 < TC) ? t + 2 : TC - 1;
      r0_step(buf[0], buf[1], xub, tlA, Bf, xuA, Bfx, bx, stx, t - 1, t > 0, skip2,
              out, bt, q, col, n, false);
      RAW_BAR();
      int tlB = (t + 3 < TC) ? t + 3 : TC - 1;
      bool lastB = (c == NCH - 1) && (t + 1 == TC - 1);
      r0_step(buf[1], buf[0], xub, tlB, Bf, xuB, Bfx, bx, stx, t, true, skip2,
              out, bt, q, col, n, lastB);
      RAW_BAR();
    }
    // final x1 phase for h(TC-1) (in buf[0])
    {
      h8 A[5];
#pragma unroll
      for (int kt = 0; kt < 5; kt++)
        A[kt] = *(const h8*)(buf[0] + col * S0 + kt * 32 + q * 8);
#pragma unroll
      for (int tt = 0; tt < 2; tt++) {
        float b = bx[tt];
        f4 ax = {b, b, b, b};
#pragma unroll
        for (int kt = 0; kt < 5; kt++) ax = MFMA(A[kt], Bfx[tt][kt], ax);
        h4 o;
#pragma unroll
        for (int rr = 0; rr < 4; rr++) o[rr] = (f16)ax[rr];
        if (!(skip2 && tt == 1))
          *(h4*)(stx[tt] + (size_t)(TC - 1) * XUST1) = o;
      }
    }
    for (int idx = tid; idx < 16 * S0; idx += 640)
      H0S[(size_t)bt * 16 * S0 + idx] = buf[0][idx];

  } else if (wg < 2 * NBT) {  // ================= r12(c-1) =================
    int cc = c - 1;
    if (cc < 0 || cc >= NCH) return;
    f16(*buf)[16 * S2] = (f16(*)[16 * S2])smem;
    int bt = wg - NBT;
    int w = g;  // wave id 0..9 (8,9 idle in compute)
    const f16* XU1r = (cc & 1) ? XU1b : XU1a;
    h8 Bf[3][4];
    float bn0 = 0.f, bn1 = 0.f, bn2 = 0.f;
    int n = w * 16 + col;
    const f16* xub[3] = {XU1r, XU1r, XU1r};
    if (w < 7) {
#pragma unroll
      for (int mat = 0; mat < 3; mat++)
#pragma unroll
        for (int kt = 0; kt < 4; kt++)
          Bf[mat][kt] = pk[OFF_R12A + ((w * 3 + mat) * 4 + kt) * 64 + lane];
      int nn = n < 98 ? n : 98;
#pragma unroll
      for (int mat = 0; mat < 3; mat++) {
        int cm = mat * 99 + nn;
        xub[mat] = XU1r + ((size_t)bt * NT1P + (cm >> 4)) * 256 +
                   (q * 16 + (cm & 15)) * 4;
      }
    } else if (w == 7) {
#pragma unroll
      for (int mat = 0; mat < 3; mat++)
#pragma unroll
        for (int kt = 0; kt < 4; kt++)
          Bf[mat][kt] = pk[OFF_R12B + (mat * 4 + kt) * 64 + lane];
      bn0 = (col < Nm) ? -2.f * c1[col] : 0.f;
      bn1 = (col < Nm) ? -2.f * c2[col] : 0.f;
      bn2 = (col < Nm) ? -(ts * ca[col] + cb[col]) : 0.f;
    }
    for (int idx = tid; idx < 2 * 16 * S2; idx += 640)
      ((f16*)buf)[idx] = (cc == 0) ? (f16)0.f : H12S[(size_t)bt * 2 * 16 * S2 + idx];
    __syncthreads();

    h4 xuA[3], xuB[3];
    if (w < 7) {
#pragma unroll
      for (int mat = 0; mat < 3; mat++) {
        xuA[mat] = *(const h4*)(xub[mat]);
        xuB[mat] = *(const h4*)(xub[mat] + XUST1);
      }
    }
    for (int t = 0; t < TC; t += 2) {
      if (w < 7) {
        int tlA = (t + 2 < TC) ? t + 2 : TC - 1;
        r12l1_step(buf[0], buf[1], xub, tlA, Bf, xuA, out, bt, q, col, n, false);
      }
      RAW_BAR();
      if (w == 7)
        r12l2_step(buf[1], buf[0], out, Bf, bn0, bn1, bn2, cc * TC + t, bt, col, q,
                   false);
      if (w < 7) {
        int tlB = (t + 3 < TC) ? t + 3 : TC - 1;
        bool lastB = (cc == NCH - 1) && (t + 1 == TC - 1);
        r12l1_step(buf[1], buf[0], xub, tlB, Bf, xuB, out, bt, q, col, n, lastB);
      }
      RAW_BAR();
      if (w == 7)
        r12l2_step(buf[0], buf[1], out, Bf, bn0, bn1, bn2, cc * TC + t + 1, bt, col,
                   q, (cc == NCH - 1) && (t + 1 == TC - 1));
    }
    __syncthreads();
    for (int idx = tid; idx < 2 * 16 * S2; idx += 640)
      H12S[(size_t)bt * 2 * 16 * S2 + idx] = ((f16*)buf)[idx];

  } else {  // ================= x0(c+1) =================
    int cn = c + 1;
    if (cn >= NCH) return;
    f16* stg = (f16*)smem;  // 16 x 136 halves
    f16* XU0w = (cn & 1) ? XU0b : XU0a;
    int wgx = wg - 2 * NBT;  // 0..127
    bool w9 = (g == 9);
    h8 Bfx0[3][4];
    float bx0[3];
    int tis[3];
#pragma unroll
    for (int tt = 0; tt < 3; tt++) {
      int ti = 3 * g + tt;
      if (ti > 27) ti = 27;
      tis[tt] = ti;
#pragma unroll
      for (int kt = 0; kt < 4; kt++)
        Bfx0[tt][kt] = pk[OFF_X0 + (ti * 4 + kt) * 64 + lane];
      bx0[tt] = xbias(ti * 16 + col, 149, 447, b1_0, b2_0, ba_0, bb_0, ts);
    }
    for (int i = 0; i < 8; i++) {
      int mt = wgx * 8 + i;
      int tl = mt >> 4, bt = mt & 15;
      int tg = cn * TC + tl;
      if (tid < 256) {
        int sr = tid >> 4, scv = (tid & 15) * 8;
        const float* xp = x + ((size_t)(bt * 16 + sr) * Tsz + tg) * IN_DIM + scv;
        h8 hv;
#pragma unroll
        for (int j = 0; j < 8; j++) hv[j] = (f16)xp[j];
        *(h8*)(stg + sr * 136 + scv) = hv;
      }
      __syncthreads();
      h8 A[4];
#pragma unroll
      for (int kt = 0; kt < 4; kt++)
        A[kt] = *(const h8*)(stg + col * 136 + kt * 32 + q * 8);
#pragma unroll
      for (int tt = 0; tt < 3; tt++) {
        float b = bx0[tt];
        f4 ax = {b, b, b, b};
#pragma unroll
        for (int kt = 0; kt < 4; kt++) ax = MFMA(A[kt], Bfx0[tt][kt], ax);
        h4 o;
#pragma unroll
        for (int rr = 0; rr < 4; rr++) o[rr] = (f16)ax[rr];
        if (!(w9 && tt > 0))
          *(h4*)(XU0w + ((size_t)mt * NT0P + tis[tt]) * 256 + lane * 4) = o;
      }
      __syncthreads();
    }
  }
}

extern "C" void kernel_launch(void* const* d_in, const int* in_sizes, int n_in,
                              void* d_out, int out_size, void* d_ws, size_t ws_size,
                              hipStream_t stream) {
  const float* w1_0 = (const float*)d_in[0];
  const float* w2_0 = (const float*)d_in[1];
  const float* wa_0 = (const float*)d_in[2];
  const float* wb_0 = (const float*)d_in[3];
  const float* b1_0 = (const float*)d_in[4];
  const float* b2_0 = (const float*)d_in[5];
  const float* ba_0 = (const float*)d_in[6];
  const float* bb_0 = (const float*)d_in[7];
  const int* m0 = (const int*)d_in[8];
  const float* w1_1 = (const float*)d_in[9];
  const float* w2_1 = (const float*)d_in[10];
  const float* wa_1 = (const float*)d_in[11];
  const float* wb_1 = (const float*)d_in[12];
  const float* b1_1 = (const float*)d_in[13];
  const float* b2_1 = (const float*)d_in[14];
  const float* ba_1 = (const float*)d_in[15];
  const float* bb_1 = (const float*)d_in[16];
  const int* m1 = (const int*)d_in[17];
  const float* w1_2 = (const float*)d_in[18];
  const float* w2_2 = (const float*)d_in[19];
  const float* wa_2 = (const float*)d_in[20];
  const float* wb_2 = (const float*)d_in[21];
  const float* c1 = (const float*)d_in[22];
  const float* c2 = (const float*)d_in[23];
  const float* ca = (const float*)d_in[24];
  const float* cb = (const float*)d_in[25];
  const int* m2 = (const int*)d_in[26];
  const float* x = (const float*)d_in[27];
  const float* dt = (const float*)d_in[28];
  float* out = (float*)d_out;

  f16* XU0a = (f16*)d_ws;
  f16* XU0b = XU0a + XU0_H;
  f16* XU1a = XU0b + XU0_H;
  f16* XU1b = XU1a + XU1_H;
  f16* H0S = XU1b + XU1_H;
  f16* H12S = H0S + H0S_H;
  f16* PK = H12S + H12S_H;
  const h8* pk = (const h8*)PK;

  pack_kernel<<<(NFRAG + 255) / 256, 256, 0, stream>>>(
      w1_0, w2_0, wa_0, wb_0, m0, w1_1, w2_1, wa_1, wb_1, m1,
      w1_2, w2_2, wa_2, wb_2, m2, dt, PK);

  for (int c = -1; c <= NCH; c++) {
    R_kernel<<<160, 640, 0, stream>>>(pk, x, b1_0, b2_0, ba_0, bb_0, b1_1, b2_1,
                                      ba_1, bb_1, c1, c2, ca, cb, dt, XU0a, XU0b,
                                      XU1a, XU1b, H0S, H12S, out, c);
  }
}

// Round 8
// 1329.730 us; speedup vs baseline: 1.0637x; 1.0637x over previous
//
#include <hip/hip_runtime.h>
#include <cmath>

// CfC-NCP RNN, phase-decomposed + chunk-pipelined (R8 = R6-base + dual-tile R):
//   pack (once): weight fragments -> h8; mats pre-scaled (-2*w1,-2*w2,-(ts*wa+wb)).
//   X(-1): x0(0).  c=0..4: R(c) = [r0(c) WGs 0-7, 2 batch-tiles each |
//                                  r12(c-1) WGs 8-15, 2 batch-tiles each];
//   c<4: X(c) = [x1(c) WGs 0-511 | x0(c+1) WGs 512-1023].
// Dual-tile R: two independent dependency chains per wave hide the
// ds_read->MFMA->trans->ds_write latency that left R6 ~64% stalled; weights
// shared across tiles. R7's single-launch fusion REGRESSED (bulk GEMM co-resident
// with the recurrence CUs) — reverted.
// fp16 MFMA inputs, fp32 accum. Workspace ~65 MB. TC=128, NCH=4.

typedef _Float16 f16;
typedef f16 h4 __attribute__((ext_vector_type(4)));
typedef f16 h8 __attribute__((ext_vector_type(8)));
typedef float f4 __attribute__((ext_vector_type(4)));

#define MFMA(a, b, c) __builtin_amdgcn_mfma_f32_16x16x32_f16(a, b, c, 0, 0, 0)
// LDS-only barrier: waves drain their own LDS ops then sync; global ops stay in flight.
#define RAW_BAR() asm volatile("s_waitcnt lgkmcnt(0)\n\ts_barrier" ::: "memory")

constexpr int IN_DIM = 128, Ni = 149, Nc = 99, Nm = 8;
constexpr int CAT0 = 277, CAT1 = 248, CAT2 = 107;
constexpr int Bsz = 256, Tsz = 512;
constexpr int TC = 128, NCH = 4, NBT = 16;
constexpr int NT0 = 30, NT1 = 21;        // fragment tile-columns (3 mats x n-tiles)
constexpr int S0 = 168, S2 = 136;        // LDS row strides (halves)
constexpr size_t XU0_HALVES = (size_t)TC * NBT * NT0 * 256;
constexpr size_t NH0_HALVES = (size_t)TC * NBT * 16 * 160;
constexpr size_t XU1_HALVES = (size_t)TC * NBT * NT1 * 256;
constexpr size_t H0S_HALVES = (size_t)NBT * 16 * S0;
constexpr size_t H12S_HALVES = (size_t)NBT * 2 * 16 * S2;
constexpr size_t YOFF = (size_t)Bsz * Tsz * 8;
constexpr size_t STR0 = (size_t)NBT * NT0 * 256;  // XU0 per-t stride (halves)
constexpr size_t STR1 = (size_t)NBT * NT1 * 256;  // XU1 per-t stride

// packed-fragment segment offsets (h8 units); mat2 = merged -(ts*wa+wb)
constexpr int OFF_X0 = 0;          // [mat3][nt10][kt4][lane64]
constexpr int OFF_R0 = 7680;       // [g10][mat3][kt5][lane64]
constexpr int OFF_X1 = 17280;      // [mat3][nt7][kt5][lane64]
constexpr int OFF_R12A = 24000;    // [w7][mat3][kt4][lane64]
constexpr int OFF_R12B = 29376;    // [mat3][kt4][lane64]
constexpr int NFRAG = 30144;

__device__ inline float rcpf_(float x) { return __builtin_amdgcn_rcpf(x); }
// h = ff1 + (ff2-ff1)*ti, ff=(1-e)/(1+e), ti=1/(1+e2); a0=-2u1, a1=-2u2, a2=-z
__device__ __forceinline__ float cfc_h(float a0, float a1, float a2) {
  float e0 = __expf(a0), e1 = __expf(a1), e2 = __expf(a2);
  float pa = 1.f + e0, ma = 1.f - e0;
  float pb = 1.f + e1, mb = 1.f - e1;
  float pc = 1.f + e2;
  float num = fmaf(ma * pb, e2, mb * pa);
  return num * rcpf_(pa * pb * pc);
}
__device__ __forceinline__ float tanhp_(float x) {
  float e = __expf(-2.f * x);
  return (1.f - e) * rcpf_(1.f + e);
}

// ---------------- pack ----------------------------------------------------------------
__global__ __launch_bounds__(256) void pack_kernel(
    const float* __restrict__ w1_0, const float* __restrict__ w2_0,
    const float* __restrict__ wa_0, const float* __restrict__ wb_0,
    const int* __restrict__ m0,
    const float* __restrict__ w1_1, const float* __restrict__ w2_1,
    const float* __restrict__ wa_1, const float* __restrict__ wb_1,
    const int* __restrict__ m1,
    const float* __restrict__ w1_2, const float* __restrict__ w2_2,
    const float* __restrict__ wa_2, const float* __restrict__ wb_2,
    const int* __restrict__ m2, const float* __restrict__ dtp,
    f16* __restrict__ PK) {
  int idx = blockIdx.x * 256 + threadIdx.x;
  if (idx >= NFRAG) return;
  int lane = idx & 63, col = lane & 15, q = lane >> 4;
  float ts = dtp[0];
  const float* Wa = nullptr;
  const float* Wb = nullptr;
  const int* M = nullptr;
  int ld, n, nmax, k0, kmax;
  int mat;
  if (idx < OFF_R0) {  // x0 input-part
    int p = idx >> 6;
    mat = p / 40; int nt = (p >> 2) % 10, kt = p & 3;
    ld = CAT0; n = nt * 16 + col; nmax = Ni; k0 = kt * 32 + q * 8; kmax = IN_DIM;
    if (mat == 0) { Wa = w1_0; M = m0; }
    else if (mat == 1) { Wa = w2_0; M = m0; }
    else { Wa = wa_0; Wb = wb_0; }
  } else if (idx < OFF_X1) {  // r0 recurrent-part
    int p = (idx - OFF_R0) >> 6;
    int g = p / 15; mat = (p / 5) % 3; int kt = p % 5;
    ld = CAT0; n = g * 16 + col; nmax = Ni; k0 = IN_DIM + kt * 32 + q * 8; kmax = CAT0;
    if (mat == 0) Wa = w1_0;
    else if (mat == 1) Wa = w2_0;
    else { Wa = wa_0; Wb = wb_0; }
  } else if (idx < OFF_R12A) {  // x1 input-part
    int p = (idx - OFF_X1) >> 6;
    mat = p / 35; int nt = (p / 5) % 7, kt = p % 5;
    ld = CAT1; n = nt * 16 + col; nmax = Nc; k0 = kt * 32 + q * 8; kmax = Ni;
    if (mat == 0) { Wa = w1_1; M = m1; }
    else if (mat == 1) { Wa = w2_1; M = m1; }
    else { Wa = wa_1; Wb = wb_1; }
  } else if (idx < OFF_R12B) {  // r12 layer1 recurrent-part
    int p = (idx - OFF_R12A) >> 6;
    int wv = p / 12; mat = (p / 4) % 3; int kt = p & 3;
    ld = CAT1; n = wv * 16 + col; nmax = Nc; k0 = Ni + kt * 32 + q * 8; kmax = CAT1;
    if (mat == 0) Wa = w1_1;
    else if (mat == 1) Wa = w2_1;
    else { Wa = wa_1; Wb = wb_1; }
  } else {  // r12 layer2 (full cat)
    int p = (idx - OFF_R12B) >> 6;
    mat = p / 4; int kt = p & 3;
    ld = CAT2; n = col; nmax = Nm; k0 = kt * 32 + q * 8; kmax = CAT2;
    if (mat == 0) { Wa = w1_2; M = m2; }
    else if (mat == 1) { Wa = w2_2; M = m2; }
    else { Wa = wa_2; Wb = wb_2; }
  }
  h8 r;
#pragma unroll
  for (int j = 0; j < 8; j++) {
    int k = k0 + j;
    float v = 0.f;
    if (n < nmax && k < kmax) {
      if (mat < 2) {
        v = Wa[(size_t)n * ld + k];
        if (M) v *= (float)M[(size_t)n * ld + k];
        v *= -2.f;
      } else {
        v = -(ts * Wa[(size_t)n * ld + k] + Wb[(size_t)n * ld + k]);
      }
    }
    r[j] = (f16)v;
  }
  ((h8*)PK)[idx] = r;
}

// ---------------- X: [x1(c) | x0(c+1)] on disjoint WG ranges, 3 waves/WG -------------
__global__ __launch_bounds__(192, 2) void X_kernel(
    const h8* __restrict__ pk, const float* __restrict__ x,
    const f16* __restrict__ NH0, f16* __restrict__ XU0, f16* __restrict__ XU1,
    const float* __restrict__ b1_0, const float* __restrict__ b2_0,
    const float* __restrict__ ba_0, const float* __restrict__ bb_0,
    const float* __restrict__ b1_1, const float* __restrict__ b2_1,
    const float* __restrict__ ba_1, const float* __restrict__ bb_1,
    const float* __restrict__ dtp, int c) {
  __shared__ f16 stg[16 * 136];
  int tid = threadIdx.x;
  int w = tid >> 6, lane = tid & 63, col = lane & 15, q = lane >> 4;
  int wg = blockIdx.x;
  float ts = dtp[0];
  if (wg < 512) {  // ---- x1 for chunk c (wave w = mat) ----
    if (c < 0) return;
    h8 Bf[7][5];
    float bias[7];
#pragma unroll
    for (int nt = 0; nt < 7; nt++) {
#pragma unroll
      for (int kt = 0; kt < 5; kt++)
        Bf[nt][kt] = pk[OFF_X1 + ((w * 7 + nt) * 5 + kt) * 64 + lane];
      int n = nt * 16 + col;
      bias[nt] = (n < Nc) ? (w == 0 ? -2.f * b1_1[n]
                                    : (w == 1 ? -2.f * b2_1[n]
                                              : -(ts * ba_1[n] + bb_1[n])))
                          : 0.f;
    }
    for (int i = 0; i < 4; i++) {
      int mt = wg * 4 + i;
      const f16* Ab = NH0 + (size_t)mt * 2560;
      h8 A[5];
#pragma unroll
      for (int kt = 0; kt < 5; kt++)
        A[kt] = *(const h8*)(Ab + col * 160 + kt * 32 + q * 8);
#pragma unroll
      for (int nt = 0; nt < 7; nt++) {
        float b = bias[nt];
        f4 acc = {b, b, b, b};
#pragma unroll
        for (int kt = 0; kt < 5; kt++) acc = MFMA(A[kt], Bf[nt][kt], acc);
        h4 o;
#pragma unroll
        for (int rr = 0; rr < 4; rr++) o[rr] = (f16)acc[rr];
        *(h4*)(XU1 + ((size_t)mt * NT1 + w * 7 + nt) * 256 + lane * 4) = o;
      }
    }
  } else {  // ---- x0 for chunk c+1 (wave w = mat) ----
    int cn = c + 1;
    if (cn >= NCH) return;
    int bx = wg - 512;
    h8 Bf[10][4];
    float bias[10];
#pragma unroll
    for (int nt = 0; nt < 10; nt++) {
#pragma unroll
      for (int kt = 0; kt < 4; kt++)
        Bf[nt][kt] = pk[OFF_X0 + ((w * 10 + nt) * 4 + kt) * 64 + lane];
      int n = nt * 16 + col;
      bias[nt] = (n < Ni) ? (w == 0 ? -2.f * b1_0[n]
                                    : (w == 1 ? -2.f * b2_0[n]
                                              : -(ts * ba_0[n] + bb_0[n])))
                          : 0.f;
    }
    for (int i = 0; i < 4; i++) {
      int mt = bx * 4 + i;
      int tl = mt >> 4, bt = mt & 15;
      int tg = cn * TC + tl;
      if (tid < 128) {
        int sr = tid >> 3, sc = (tid & 7) * 16;
        const float* xp = x + ((size_t)(bt * 16 + sr) * Tsz + tg) * IN_DIM + sc;
        h8 hv0, hv1;
#pragma unroll
        for (int j = 0; j < 8; j++) hv0[j] = (f16)xp[j];
#pragma unroll
        for (int j = 0; j < 8; j++) hv1[j] = (f16)xp[8 + j];
        *(h8*)(stg + sr * 136 + sc) = hv0;
        *(h8*)(stg + sr * 136 + sc + 8) = hv1;
      }
      __syncthreads();
      h8 A[4];
#pragma unroll
      for (int kt = 0; kt < 4; kt++)
        A[kt] = *(const h8*)(stg + col * 136 + kt * 32 + q * 8);
#pragma unroll
      for (int nt = 0; nt < 10; nt++) {
        float b = bias[nt];
        f4 acc = {b, b, b, b};
#pragma unroll
        for (int kt = 0; kt < 4; kt++) acc = MFMA(A[kt], Bf[nt][kt], acc);
        h4 o;
#pragma unroll
        for (int rr = 0; rr < 4; rr++) o[rr] = (f16)acc[rr];
        *(h4*)(XU0 + ((size_t)mt * NT0 + w * 10 + nt) * 256 + lane * 4) = o;
      }
      __syncthreads();
    }
  }
}

// ------- r0 one step, TWO tiles: independent chains hide latency ---------------------
__device__ __forceinline__ void r0_step2(
    const f16* br0, const f16* br1, f16* bw0, f16* bw1,
    const f16* const (&xb0)[3], const f16* const (&xb1)[3], int tload,
    const h8 (&Bf)[3][5], h4 (&xu0)[3], h4 (&xu1)[3],
    f16* __restrict__ NH0, float* __restrict__ out,
    int t, int bt0, int bt1, int q, int col, int n, bool last) {
  h8 A0[5], A1[5];
#pragma unroll
  for (int kt = 0; kt < 5; kt++) {
    A0[kt] = *(const h8*)(br0 + col * S0 + kt * 32 + q * 8);
    A1[kt] = *(const h8*)(br1 + col * S0 + kt * 32 + q * 8);
  }
  f4 a00 = {(float)xu0[0][0], (float)xu0[0][1], (float)xu0[0][2], (float)xu0[0][3]};
  f4 a01 = {(float)xu0[1][0], (float)xu0[1][1], (float)xu0[1][2], (float)xu0[1][3]};
  f4 a02 = {(float)xu0[2][0], (float)xu0[2][1], (float)xu0[2][2], (float)xu0[2][3]};
  f4 a10 = {(float)xu1[0][0], (float)xu1[0][1], (float)xu1[0][2], (float)xu1[0][3]};
  f4 a11 = {(float)xu1[1][0], (float)xu1[1][1], (float)xu1[1][2], (float)xu1[1][3]};
  f4 a12 = {(float)xu1[2][0], (float)xu1[2][1], (float)xu1[2][2], (float)xu1[2][3]};
#pragma unroll
  for (int mat = 0; mat < 3; mat++) {
    xu0[mat] = *(const h4*)(xb0[mat] + (size_t)tload * STR0);
    xu1[mat] = *(const h4*)(xb1[mat] + (size_t)tload * STR0);
  }
#pragma unroll
  for (int kt = 0; kt < 5; kt++) {
    a00 = MFMA(A0[kt], Bf[0][kt], a00);
    a01 = MFMA(A0[kt], Bf[1][kt], a01);
    a02 = MFMA(A0[kt], Bf[2][kt], a02);
    a10 = MFMA(A1[kt], Bf[0][kt], a10);
    a11 = MFMA(A1[kt], Bf[1][kt], a11);
    a12 = MFMA(A1[kt], Bf[2][kt], a12);
  }
  f16* nh0 = NH0 + ((size_t)t * NBT + bt0) * 2560;
  f16* nh1 = NH0 + ((size_t)t * NBT + bt1) * 2560;
#pragma unroll
  for (int r = 0; r < 4; r++) {
    int m = q * 4 + r;
    float h0 = cfc_h(a00[r], a01[r], a02[r]);
    float h1 = cfc_h(a10[r], a11[r], a12[r]);
    f16 g0 = (f16)h0, g1 = (f16)h1;
    bw0[m * S0 + n] = g0;
    bw1[m * S0 + n] = g1;
    nh0[m * 160 + n] = g0;
    nh1[m * 160 + n] = g1;
    if (last && n < Ni) {
      out[YOFF + (size_t)(bt0 * 16 + m) * 256 + n] = h0;
      out[YOFF + (size_t)(bt1 * 16 + m) * 256 + n] = h1;
    }
  }
}

// ------- r12 layer1 one step, TWO tiles ----------------------------------------------
__device__ __forceinline__ void r12l1_step2(
    const f16* br0, const f16* br1, f16* bw0, f16* bw1,
    const f16* const (&xb0)[3], const f16* const (&xb1)[3], int tload,
    const h8 (&Bf)[3][4], h4 (&xu0)[3], h4 (&xu1)[3],
    float* __restrict__ out, int bt0, int bt1, int q, int col, int n, bool last) {
  h8 A0[4], A1[4];
#pragma unroll
  for (int kt = 0; kt < 4; kt++) {
    A0[kt] = *(const h8*)(br0 + col * S2 + kt * 32 + q * 8);
    A1[kt] = *(const h8*)(br1 + col * S2 + kt * 32 + q * 8);
  }
  f4 a00 = {(float)xu0[0][0], (float)xu0[0][1], (float)xu0[0][2], (float)xu0[0][3]};
  f4 a01 = {(float)xu0[1][0], (float)xu0[1][1], (float)xu0[1][2], (float)xu0[1][3]};
  f4 a02 = {(float)xu0[2][0], (float)xu0[2][1], (float)xu0[2][2], (float)xu0[2][3]};
  f4 a10 = {(float)xu1[0][0], (float)xu1[0][1], (float)xu1[0][2], (float)xu1[0][3]};
  f4 a11 = {(float)xu1[1][0], (float)xu1[1][1], (float)xu1[1][2], (float)xu1[1][3]};
  f4 a12 = {(float)xu1[2][0], (float)xu1[2][1], (float)xu1[2][2], (float)xu1[2][3]};
#pragma unroll
  for (int mat = 0; mat < 3; mat++) {
    xu0[mat] = *(const h4*)(xb0[mat] + (size_t)tload * STR1);
    xu1[mat] = *(const h4*)(xb1[mat] + (size_t)tload * STR1);
  }
#pragma unroll
  for (int kt = 0; kt < 4; kt++) {
    a00 = MFMA(A0[kt], Bf[0][kt], a00);
    a01 = MFMA(A0[kt], Bf[1][kt], a01);
    a02 = MFMA(A0[kt], Bf[2][kt], a02);
    a10 = MFMA(A1[kt], Bf[0][kt], a10);
    a11 = MFMA(A1[kt], Bf[1][kt], a11);
    a12 = MFMA(A1[kt], Bf[2][kt], a12);
  }
#pragma unroll
  for (int r = 0; r < 4; r++) {
    int m = q * 4 + r;
    float h0 = cfc_h(a00[r], a01[r], a02[r]);
    float h1 = cfc_h(a10[r], a11[r], a12[r]);
    if (n < Nc) {
      bw0[m * S2 + n] = (f16)h0;
      bw1[m * S2 + n] = (f16)h1;
      if (last) {
        out[YOFF + (size_t)(bt0 * 16 + m) * 256 + Ni + n] = h0;
        out[YOFF + (size_t)(bt1 * 16 + m) * 256 + Ni + n] = h1;
      }
    }
  }
}

// ------- r12 layer2 one step, TWO tiles ----------------------------------------------
__device__ __forceinline__ void r12l2_step2(
    const f16* rb0, const f16* rb1, f16* wb0, f16* wb1, float* __restrict__ out,
    const h8 (&Bf)[3][4], float bn0, float bn1, float bn2, int tg, int bt0, int bt1,
    int col, int q, bool last) {
  h8 A0[4], A1[4];
#pragma unroll
  for (int kt = 0; kt < 4; kt++) {
    A0[kt] = *(const h8*)(rb0 + col * S2 + kt * 32 + q * 8);
    A1[kt] = *(const h8*)(rb1 + col * S2 + kt * 32 + q * 8);
  }
  f4 a00 = {bn0, bn0, bn0, bn0}, a01 = {bn1, bn1, bn1, bn1}, a02 = {bn2, bn2, bn2, bn2};
  f4 a10 = a00, a11 = a01, a12 = a02;
#pragma unroll
  for (int kt = 0; kt < 4; kt++) {
    a00 = MFMA(A0[kt], Bf[0][kt], a00);
    a01 = MFMA(A0[kt], Bf[1][kt], a01);
    a02 = MFMA(A0[kt], Bf[2][kt], a02);
    a10 = MFMA(A1[kt], Bf[0][kt], a10);
    a11 = MFMA(A1[kt], Bf[1][kt], a11);
    a12 = MFMA(A1[kt], Bf[2][kt], a12);
  }
#pragma unroll
  for (int r = 0; r < 4; r++) {
    int m = q * 4 + r;
    float h0 = cfc_h(a00[r], a01[r], a02[r]);
    float h1 = cfc_h(a10[r], a11[r], a12[r]);
    if (col < Nm) {
      out[((size_t)(bt0 * 16 + m) * Tsz + tg) * 8 + col] = tanhp_(h0);
      out[((size_t)(bt1 * 16 + m) * Tsz + tg) * 8 + col] = tanhp_(h1);
      wb0[m * S2 + Nc + col] = (f16)h0;
      wb1[m * S2 + Nc + col] = (f16)h1;
      if (last) {
        out[YOFF + (size_t)(bt0 * 16 + m) * 256 + Ni + Nc + col] = h0;
        out[YOFF + (size_t)(bt1 * 16 + m) * 256 + Ni + Nc + col] = h1;
      }
    }
  }
}

// ---------------- R: [r0(c) WGs 0-7 | r12(c-1) WGs 8-15], 2 tiles per WG -------------
__global__ __launch_bounds__(640) void R_kernel(
    const h8* __restrict__ pk,
    const float* __restrict__ c1, const float* __restrict__ c2,
    const float* __restrict__ ca, const float* __restrict__ cb,
    const float* __restrict__ dtp, const f16* __restrict__ XU0,
    const f16* __restrict__ XU1, f16* __restrict__ NH0,
    f16* __restrict__ H0S, f16* __restrict__ H12S, float* __restrict__ out, int c) {
  __shared__ __align__(16) char smem[2 * 2 * 16 * S0 * 2];  // [tile][parity][16*S]
  int tid = threadIdx.x;
  int g = tid >> 6, lane = tid & 63, col = lane & 15, q = lane >> 4;
  int wg = blockIdx.x;

  if (wg < 8) {  // ================= r0, chunk c, tiles 2wg/2wg+1 =================
    if (c >= NCH) return;
    typedef f16 (*BufT)[16 * S0];
    BufT B0 = (BufT)smem;                       // tile0: [parity][16*S0]
    BufT B1 = (BufT)(smem + 2 * 16 * S0 * 2);   // tile1
    int bt0 = 2 * wg, bt1 = 2 * wg + 1;
    int n = g * 16 + col;
    h8 Bf[3][5];
#pragma unroll
    for (int mat = 0; mat < 3; mat++)
#pragma unroll
      for (int kt = 0; kt < 5; kt++)
        Bf[mat][kt] = pk[OFF_R0 + ((g * 3 + mat) * 5 + kt) * 64 + lane];

    const f16* xb0[3];
    const f16* xb1[3];
#pragma unroll
    for (int mat = 0; mat < 3; mat++) {
      xb0[mat] = XU0 + ((size_t)bt0 * NT0 + mat * 10 + g) * 256 + lane * 4;
      xb1[mat] = XU0 + ((size_t)bt1 * NT0 + mat * 10 + g) * 256 + lane * 4;
    }
    for (int idx = tid; idx < 16 * S0; idx += 640) {
      B0[0][idx] = (c == 0) ? (f16)0.f : H0S[(size_t)bt0 * 16 * S0 + idx];
      B1[0][idx] = (c == 0) ? (f16)0.f : H0S[(size_t)bt1 * 16 * S0 + idx];
      B0[1][idx] = (f16)0.f;
      B1[1][idx] = (f16)0.f;
    }
    __syncthreads();

    h4 xuA0[3], xuA1[3], xuB0[3], xuB1[3];      // depth-2 prefetch per tile
#pragma unroll
    for (int mat = 0; mat < 3; mat++) {
      xuA0[mat] = *(const h4*)(xb0[mat]);
      xuA1[mat] = *(const h4*)(xb1[mat]);
      xuB0[mat] = *(const h4*)(xb0[mat] + STR0);
      xuB1[mat] = *(const h4*)(xb1[mat] + STR0);
    }

    for (int t = 0; t < TC; t += 2) {
      int tlA = (t + 2 < TC) ? t + 2 : TC - 1;
      r0_step2(B0[0], B1[0], B0[1], B1[1], xb0, xb1, tlA, Bf, xuA0, xuA1, NH0, out,
               t, bt0, bt1, q, col, n, false);
      RAW_BAR();
      int tlB = (t + 3 < TC) ? t + 3 : TC - 1;
      bool lastB = (c == NCH - 1) && (t + 1 == TC - 1);
      r0_step2(B0[1], B1[1], B0[0], B1[0], xb0, xb1, tlB, Bf, xuB0, xuB1, NH0, out,
               t + 1, bt0, bt1, q, col, n, lastB);
      RAW_BAR();
    }
    for (int idx = tid; idx < 16 * S0; idx += 640) {
      H0S[(size_t)bt0 * 16 * S0 + idx] = B0[0][idx];
      H0S[(size_t)bt1 * 16 * S0 + idx] = B1[0][idx];
    }

  } else {  // ================= r12, chunk cc = c-1, tiles 2(wg-8)/2(wg-8)+1 ==========
    int cc = c - 1;
    if (cc < 0) return;
    typedef f16 (*BufT)[16 * S2];
    BufT B0 = (BufT)smem;
    BufT B1 = (BufT)(smem + 2 * 16 * S2 * 2);
    int bt0 = 2 * (wg - 8), bt1 = bt0 + 1;
    int w = g;  // wave id 0..9 (8,9 idle)
    float ts = dtp[0];
    h8 Bf[3][4];
    float bn0 = 0.f, bn1 = 0.f, bn2 = 0.f;
    int n = w * 16 + col;
    const f16* xb0[3] = {XU1, XU1, XU1};
    const f16* xb1[3] = {XU1, XU1, XU1};
    if (w < 7) {
#pragma unroll
      for (int mat = 0; mat < 3; mat++) {
#pragma unroll
        for (int kt = 0; kt < 4; kt++)
          Bf[mat][kt] = pk[OFF_R12A + ((w * 3 + mat) * 4 + kt) * 64 + lane];
        xb0[mat] = XU1 + ((size_t)bt0 * NT1 + mat * 7 + w) * 256 + lane * 4;
        xb1[mat] = XU1 + ((size_t)bt1 * NT1 + mat * 7 + w) * 256 + lane * 4;
      }
    } else if (w == 7) {
#pragma unroll
      for (int mat = 0; mat < 3; mat++)
#pragma unroll
        for (int kt = 0; kt < 4; kt++)
          Bf[mat][kt] = pk[OFF_R12B + (mat * 4 + kt) * 64 + lane];
      bn0 = (col < Nm) ? -2.f * c1[col] : 0.f;
      bn1 = (col < Nm) ? -2.f * c2[col] : 0.f;
      bn2 = (col < Nm) ? -(ts * ca[col] + cb[col]) : 0.f;
    }
    for (int idx = tid; idx < 2 * 16 * S2; idx += 640) {
      ((f16*)B0)[idx] = (cc == 0) ? (f16)0.f : H12S[(size_t)bt0 * 2 * 16 * S2 + idx];
      ((f16*)B1)[idx] = (cc == 0) ? (f16)0.f : H12S[(size_t)bt1 * 2 * 16 * S2 + idx];
    }
    __syncthreads();

    h4 xuA0[3], xuA1[3], xuB0[3], xuB1[3];
    if (w < 7) {
#pragma unroll
      for (int mat = 0; mat < 3; mat++) {
        xuA0[mat] = *(const h4*)(xb0[mat]);
        xuA1[mat] = *(const h4*)(xb1[mat]);
        xuB0[mat] = *(const h4*)(xb0[mat] + STR1);
        xuB1[mat] = *(const h4*)(xb1[mat] + STR1);
      }
    }
    for (int t = 0; t < TC; t += 2) {
      if (w < 7) {
        int tlA = (t + 2 < TC) ? t + 2 : TC - 1;
        r12l1_step2(B0[0], B1[0], B0[1], B1[1], xb0, xb1, tlA, Bf, xuA0, xuA1, out,
                    bt0, bt1, q, col, n, false);
      }
      RAW_BAR();
      if (w == 7)
        r12l2_step2(B0[1], B1[1], B0[0], B1[0], out, Bf, bn0, bn1, bn2, cc * TC + t,
                    bt0, bt1, col, q, false);
      if (w < 7) {
        int tlB = (t + 3 < TC) ? t + 3 : TC - 1;
        bool lastB = (cc == NCH - 1) && (t + 1 == TC - 1);
        r12l1_step2(B0[1], B1[1], B0[0], B1[0], xb0, xb1, tlB, Bf, xuB0, xuB1, out,
                    bt0, bt1, q, col, n, lastB);
      }
      RAW_BAR();
      if (w == 7)
        r12l2_step2(B0[0], B1[0], B0[1], B1[1], out, Bf, bn0, bn1, bn2,
                    cc * TC + t + 1, bt0, bt1, col, q,
                    (cc == NCH - 1) && (t + 1 == TC - 1));
    }
    __syncthreads();
    for (int idx = tid; idx < 2 * 16 * S2; idx += 640) {
      H12S[(size_t)bt0 * 2 * 16 * S2 + idx] = ((f16*)B0)[idx];
      H12S[(size_t)bt1 * 2 * 16 * S2 + idx] = ((f16*)B1)[idx];
    }
  }
}

extern "C" void kernel_launch(void* const* d_in, const int* in_sizes, int n_in,
                              void* d_out, int out_size, void* d_ws, size_t ws_size,
                              hipStream_t stream) {
  const float* w1_0 = (const float*)d_in[0];
  const float* w2_0 = (const float*)d_in[1];
  const float* wa_0 = (const float*)d_in[2];
  const float* wb_0 = (const float*)d_in[3];
  const float* b1_0 = (const float*)d_in[4];
  const float* b2_0 = (const float*)d_in[5];
  const float* ba_0 = (const float*)d_in[6];
  const float* bb_0 = (const float*)d_in[7];
  const int* m0 = (const int*)d_in[8];
  const float* w1_1 = (const float*)d_in[9];
  const float* w2_1 = (const float*)d_in[10];
  const float* wa_1 = (const float*)d_in[11];
  const float* wb_1 = (const float*)d_in[12];
  const float* b1_1 = (const float*)d_in[13];
  const float* b2_1 = (const float*)d_in[14];
  const float* ba_1 = (const float*)d_in[15];
  const float* bb_1 = (const float*)d_in[16];
  const int* m1 = (const int*)d_in[17];
  const float* w1_2 = (const float*)d_in[18];
  const float* w2_2 = (const float*)d_in[19];
  const float* wa_2 = (const float*)d_in[20];
  const float* wb_2 = (const float*)d_in[21];
  const float* c1 = (const float*)d_in[22];
  const float* c2 = (const float*)d_in[23];
  const float* ca = (const float*)d_in[24];
  const float* cb = (const float*)d_in[25];
  const int* m2 = (const int*)d_in[26];
  const float* x = (const float*)d_in[27];
  const float* dt = (const float*)d_in[28];
  float* out = (float*)d_out;

  f16* XU0 = (f16*)d_ws;
  f16* NH0 = XU0 + XU0_HALVES;
  f16* XU1 = NH0 + NH0_HALVES;
  f16* H0S = XU1 + XU1_HALVES;
  f16* H12S = H0S + H0S_HALVES;
  f16* PK = H12S + H12S_HALVES;
  const h8* pk = (const h8*)PK;

  pack_kernel<<<(NFRAG + 255) / 256, 256, 0, stream>>>(
      w1_0, w2_0, wa_0, wb_0, m0, w1_1, w2_1, wa_1, wb_1, m1,
      w1_2, w2_2, wa_2, wb_2, m2, dt, PK);

  // prologue: x0(0)
  X_kernel<<<1024, 192, 0, stream>>>(pk, x, NH0, XU0, XU1, b1_0, b2_0, ba_0, bb_0,
                                     b1_1, b2_1, ba_1, bb_1, dt, -1);

  for (int c = 0; c <= NCH; c++) {
    R_kernel<<<16, 640, 0, stream>>>(pk, c1, c2, ca, cb, dt, XU0, XU1, NH0, H0S,
                                     H12S, out, c);
    if (c < NCH)
      X_kernel<<<1024, 192, 0, stream>>>(pk, x, NH0, XU0, XU1, b1_0, b2_0, ba_0,
                                         bb_0, b1_1, b2_1, ba_1, bb_1, dt, c);
  }
}